// Round 1
// baseline (495.782 us; speedup 1.0000x reference)
//
#include <hip/hip_runtime.h>
#include <hip/hip_bf16.h>

// Problem dims
#define DM    2048
#define SEQ   2048
#define NB    2
#define NH    16
#define NKVH  4
#define HD    128
#define NQKV  3072   // 2048 q cols + 1024 kv cols
#define MROWS 4096   // B*S

using f32x4  = __attribute__((ext_vector_type(4))) float;
using short8 = __attribute__((ext_vector_type(8))) short;
using ushort8 = __attribute__((ext_vector_type(8))) unsigned short;

static __device__ __forceinline__ unsigned short f2bf(float f) {
  __hip_bfloat16 h = __float2bfloat16(f);
  return *reinterpret_cast<unsigned short*>(&h);
}
static __device__ __forceinline__ float bf2f(unsigned short u) {
  union { unsigned int i; float f; } v; v.i = ((unsigned int)u) << 16; return v.f;
}

// ---------------- elementwise converts / transposes ----------------

__global__ void f32_to_bf16_vec(const float* __restrict__ src, unsigned short* __restrict__ dst, int n4) {
  int i = blockIdx.x * blockDim.x + threadIdx.x;
  if (i < n4) {
    float4 v = reinterpret_cast<const float4*>(src)[i];
    ushort4 o;
    o.x = f2bf(v.x); o.y = f2bf(v.y); o.z = f2bf(v.z); o.w = f2bf(v.w);
    reinterpret_cast<ushort4*>(dst)[i] = o;
  }
}

// dst[n][k] = bf16(src[k][n]);  src is [K][N] f32 row-major, dst rows have stride K
__global__ void transpose_f32_to_bf16(const float* __restrict__ src, unsigned short* __restrict__ dst,
                                      int K, int N) {
  __shared__ float t[32][33];
  int n0 = blockIdx.x * 32, k0 = blockIdx.y * 32;
  int tx = threadIdx.x, ty = threadIdx.y;  // 32 x 8
  for (int j = 0; j < 4; j++)
    t[ty + j * 8][tx] = src[(size_t)(k0 + ty + j * 8) * N + n0 + tx];
  __syncthreads();
  for (int j = 0; j < 4; j++)
    dst[(size_t)(n0 + ty + j * 8) * K + k0 + tx] = f2bf(t[tx][ty + j * 8]);
}

__global__ void bias_concat(const float* __restrict__ bq, const float* __restrict__ bkv, float* __restrict__ o) {
  int i = blockIdx.x * 256 + threadIdx.x;
  if (i < NQKV) o[i] = (i < DM) ? bq[i] : bkv[i - DM];
}

// ---------------- bf16 MFMA GEMM: C[M][N] = A[M][K] * Bt[N][K]^T + bias ----------------

static __device__ __forceinline__ void storeval(float* C, size_t i, float v) { C[i] = v; }
static __device__ __forceinline__ void storeval(unsigned short* C, size_t i, float v) { C[i] = f2bf(v); }

template <typename OutT>
__global__ __launch_bounds__(256) void gemm_bt(const unsigned short* __restrict__ A,
                                               const unsigned short* __restrict__ Bt,
                                               const float* __restrict__ bias,
                                               OutT* __restrict__ C, int M, int N, int K) {
  // 128x128 tile, BK=64. Pad +8 bf16 -> row stride 144B = 36 dwords -> 2-way bank alias (free).
  __shared__ __align__(16) unsigned short la[128][72];
  __shared__ __align__(16) unsigned short lb[128][72];
  int tid = threadIdx.x, lane = tid & 63, w = tid >> 6;
  int wr = w >> 1, wc = w & 1, lg = lane >> 4, ln = lane & 15;
  int m0 = blockIdx.y * 128, n0 = blockIdx.x * 128;

  f32x4 acc[4][4];
  for (int mi = 0; mi < 4; mi++)
    for (int ni = 0; ni < 4; ni++) acc[mi][ni] = (f32x4){0, 0, 0, 0};

  int r = tid >> 3, co = (tid & 7) * 8;   // 32 rows per pass, 16B per thread
  for (int kt = 0; kt < K; kt += 64) {
    for (int p = 0; p < 4; p++) {
      int row = r + p * 32;
      *reinterpret_cast<uint4*>(&la[row][co]) =
          *reinterpret_cast<const uint4*>(A + (size_t)(m0 + row) * K + kt + co);
      *reinterpret_cast<uint4*>(&lb[row][co]) =
          *reinterpret_cast<const uint4*>(Bt + (size_t)(n0 + row) * K + kt + co);
    }
    __syncthreads();
    for (int kk = 0; kk < 64; kk += 32) {
      short8 af[4], bfr[4];
      for (int mi = 0; mi < 4; mi++)
        af[mi] = *reinterpret_cast<const short8*>(&la[wr * 64 + mi * 16 + ln][kk + lg * 8]);
      for (int ni = 0; ni < 4; ni++)
        bfr[ni] = *reinterpret_cast<const short8*>(&lb[wc * 64 + ni * 16 + ln][kk + lg * 8]);
      for (int mi = 0; mi < 4; mi++)
        for (int ni = 0; ni < 4; ni++)
          acc[mi][ni] = __builtin_amdgcn_mfma_f32_16x16x32_bf16(af[mi], bfr[ni], acc[mi][ni], 0, 0, 0);
    }
    __syncthreads();
  }
  for (int mi = 0; mi < 4; mi++) {
    int mrow = m0 + wr * 64 + mi * 16 + lg * 4;
    for (int ni = 0; ni < 4; ni++) {
      int n = n0 + wc * 64 + ni * 16 + ln;
      float bv = bias ? bias[n] : 0.0f;
      for (int r4 = 0; r4 < 4; r4++)
        storeval(C, (size_t)(mrow + r4) * N + n, acc[mi][ni][r4] + bv);
    }
  }
}

// ---------------- RoPE + scatter Q,K ----------------

__global__ void rope_scatter(const unsigned short* __restrict__ QKVraw, const int* __restrict__ seq_pos,
                             unsigned short* __restrict__ Qo, unsigned short* __restrict__ Ko) {
  int bs = blockIdx.x;              // b*SEQ + s
  int b = bs >> 11, s = bs & (SEQ - 1);
  int i = threadIdx.x;              // 0..63 (one wave)
  float pos = (float)seq_pos[bs];
  float ts = powf(10000.0f, (float)i * (1.0f / 64.0f));
  float ang = pos / ts;
  float sn, cs;
  sincosf(ang, &sn, &cs);
  const unsigned short* raw = QKVraw + (size_t)bs * NQKV;
  const float qscale = 0.08838834764831845f;  // 1/sqrt(128)
  for (int h = 0; h < NH; h++) {
    float x1 = bf2f(raw[h * HD + i]);
    float x2 = bf2f(raw[h * HD + 64 + i]);
    size_t o = ((size_t)((b * NH + h) * SEQ + s)) * HD;
    Qo[o + i]      = f2bf((x1 * cs - x2 * sn) * qscale);
    Qo[o + 64 + i] = f2bf((x2 * cs + x1 * sn) * qscale);
  }
  for (int kh = 0; kh < NKVH; kh++) {
    int base = DM + kh * 256;
    float x1 = bf2f(raw[base + i]);
    float x2 = bf2f(raw[base + 64 + i]);
    size_t o = ((size_t)((b * NKVH + kh) * SEQ + s)) * HD;
    Ko[o + i]      = f2bf(x1 * cs - x2 * sn);
    Ko[o + 64 + i] = f2bf(x2 * cs + x1 * sn);
  }
}

// ---------------- V transpose: Vt[b][kv][d][s] ----------------

__global__ __launch_bounds__(256) void v_transpose(const unsigned short* __restrict__ QKVraw,
                                                   unsigned short* __restrict__ Vt) {
  __shared__ __align__(16) unsigned short lv[64][136];
  int blk = blockIdx.x;           // (b*NKVH+kvh)*32 + s_tile
  int bkv = blk >> 5;
  int s0 = (blk & 31) * 64;
  int b = bkv >> 2, kvh = bkv & 3;
  int tid = threadIdx.x;
  {
    int sl = tid >> 4, cl = (tid & 15) * 8;
    for (int p = 0; p < 4; p++) {
      int srow = sl + p * 16;
      *reinterpret_cast<uint4*>(&lv[srow][cl]) = *reinterpret_cast<const uint4*>(
          QKVraw + (size_t)(b * SEQ + s0 + srow) * NQKV + DM + kvh * 256 + 128 + cl);
    }
  }
  __syncthreads();
  {
    int dl = tid >> 3, so = (tid & 7) * 8;
    for (int p = 0; p < 4; p++) {
      int d = dl + p * 32;
      ushort8 t8;
      for (int j = 0; j < 8; j++) t8[j] = lv[so + j][d];
      *reinterpret_cast<ushort8*>(Vt + (size_t)(bkv * HD + d) * SEQ + s0 + so) = t8;
    }
  }
}

// ---------------- causal GQA flash attention ----------------
// grid (S/64, B*NH); 4 waves x 16 q-rows; KV tiles of 32.

__global__ __launch_bounds__(256) void flash_attn(const unsigned short* __restrict__ Q,
                                                  const unsigned short* __restrict__ Kr,
                                                  const unsigned short* __restrict__ Vt,
                                                  const int* __restrict__ seq_pos,
                                                  unsigned short* __restrict__ X) {
  __shared__ __align__(16) unsigned short lds_k[32][136];   // K tile [kv][d], pad->2-way
  __shared__ __align__(16) unsigned short lds_vt[128][40];  // Vt tile [d][kv]
  __shared__ __align__(16) unsigned short lds_p[4][16][40]; // per-wave P
  int tid = threadIdx.x, lane = tid & 63, w = tid >> 6;
  int bh = blockIdx.y, b = bh >> 4, h = bh & 15, kvh = h >> 2;
  int qblk = blockIdx.x * 64;
  int q0w = qblk + w * 16;
  int lg = lane >> 4, ln = lane & 15;

  // block-uniform causal bound (every wave reads all 64 block rows)
  int pmax = seq_pos[b * SEQ + qblk + (tid & 63)];
  for (int o = 32; o; o >>= 1) { int t = __shfl_xor(pmax, o); pmax = pmax > t ? pmax : t; }
  int ntiles = (pmax + 32) >> 5;
  if (ntiles > SEQ / 32) ntiles = SEQ / 32;

  int pos_r[4];
  for (int r = 0; r < 4; r++) pos_r[r] = seq_pos[b * SEQ + q0w + lg * 4 + r];

  short8 qf[4];
  {
    const unsigned short* qp = Q + ((size_t)((b * NH + h) * SEQ + q0w + ln)) * HD;
    for (int c = 0; c < 4; c++)
      qf[c] = *reinterpret_cast<const short8*>(qp + c * 32 + lg * 8);
  }

  f32x4 acc[8];
  for (int dt = 0; dt < 8; dt++) acc[dt] = (f32x4){0, 0, 0, 0};
  float m_r[4] = {-1e30f, -1e30f, -1e30f, -1e30f};
  float l_r[4] = {0, 0, 0, 0};

  const unsigned short* kbase = Kr + ((size_t)(b * NKVH + kvh)) * SEQ * HD;
  const unsigned short* vbase = Vt + ((size_t)(b * NKVH + kvh)) * HD * SEQ;

  for (int t = 0; t < ntiles; t++) {
    int kv0 = t * 32;
    {
      int kr = tid >> 4, co = (tid & 15) * 8;
      *reinterpret_cast<uint4*>(&lds_k[kr][co]) =
          *reinterpret_cast<const uint4*>(kbase + (size_t)(kv0 + kr) * HD + co);
      *reinterpret_cast<uint4*>(&lds_k[kr + 16][co]) =
          *reinterpret_cast<const uint4*>(kbase + (size_t)(kv0 + kr + 16) * HD + co);
      int d = tid >> 2, so = (tid & 3) * 8;
      *reinterpret_cast<uint4*>(&lds_vt[d][so]) =
          *reinterpret_cast<const uint4*>(vbase + (size_t)d * SEQ + kv0 + so);
      *reinterpret_cast<uint4*>(&lds_vt[d + 64][so]) =
          *reinterpret_cast<const uint4*>(vbase + (size_t)(d + 64) * SEQ + kv0 + so);
    }
    __syncthreads();

    f32x4 sa[2];
    for (int ct = 0; ct < 2; ct++) {
      sa[ct] = (f32x4){0, 0, 0, 0};
      for (int c = 0; c < 4; c++) {
        short8 kf = *reinterpret_cast<const short8*>(&lds_k[ct * 16 + ln][c * 32 + lg * 8]);
        sa[ct] = __builtin_amdgcn_mfma_f32_16x16x32_bf16(qf[c], kf, sa[ct], 0, 0, 0);
      }
    }

    float tm[4];
    for (int r = 0; r < 4; r++) {
      float v0 = (kv0 + ln <= pos_r[r]) ? sa[0][r] : -1e30f;
      float v1 = (kv0 + 16 + ln <= pos_r[r]) ? sa[1][r] : -1e30f;
      sa[0][r] = v0; sa[1][r] = v1;
      float tmx = fmaxf(v0, v1);
      tmx = fmaxf(tmx, __shfl_xor(tmx, 1));
      tmx = fmaxf(tmx, __shfl_xor(tmx, 2));
      tmx = fmaxf(tmx, __shfl_xor(tmx, 4));
      tmx = fmaxf(tmx, __shfl_xor(tmx, 8));
      tm[r] = tmx;
    }
    float corr[4];
    float pv[2][4];
    for (int r = 0; r < 4; r++) {
      float nm = fmaxf(m_r[r], tm[r]);
      corr[r] = __expf(m_r[r] - nm);
      float p0 = (kv0 + ln <= pos_r[r]) ? __expf(sa[0][r] - nm) : 0.0f;
      float p1 = (kv0 + 16 + ln <= pos_r[r]) ? __expf(sa[1][r] - nm) : 0.0f;
      m_r[r] = nm;
      pv[0][r] = p0; pv[1][r] = p1;
      float rs = p0 + p1;
      rs += __shfl_xor(rs, 1); rs += __shfl_xor(rs, 2);
      rs += __shfl_xor(rs, 4); rs += __shfl_xor(rs, 8);
      l_r[r] = l_r[r] * corr[r] + rs;
    }
    for (int dt = 0; dt < 8; dt++)
      for (int r = 0; r < 4; r++) acc[dt][r] *= corr[r];

    // P -> per-wave LDS, read back in A-fragment layout
    for (int r = 0; r < 4; r++) {
      lds_p[w][lg * 4 + r][ln]      = f2bf(pv[0][r]);
      lds_p[w][lg * 4 + r][16 + ln] = f2bf(pv[1][r]);
    }
    asm volatile("s_waitcnt lgkmcnt(0)" ::: "memory");
    __builtin_amdgcn_sched_barrier(0);
    short8 pf = *reinterpret_cast<const short8*>(&lds_p[w][ln][lg * 8]);

    for (int dt = 0; dt < 8; dt++) {
      short8 vf = *reinterpret_cast<const short8*>(&lds_vt[dt * 16 + ln][lg * 8]);
      acc[dt] = __builtin_amdgcn_mfma_f32_16x16x32_bf16(pf, vf, acc[dt], 0, 0, 0);
    }
    __syncthreads();
  }

  for (int r = 0; r < 4; r++) {
    float inv = l_r[r] > 0.0f ? 1.0f / l_r[r] : 0.0f;
    int qrow = q0w + lg * 4 + r;
    unsigned short* xp = X + ((size_t)(b * SEQ + qrow)) * DM + h * HD;
    for (int dt = 0; dt < 8; dt++) xp[dt * 16 + ln] = f2bf(acc[dt][r] * inv);
  }
}

// ---------------- launch ----------------

extern "C" void kernel_launch(void* const* d_in, const int* in_sizes, int n_in,
                              void* d_out, int out_size, void* d_ws, size_t ws_size,
                              hipStream_t stream) {
  const float* inputs  = (const float*)d_in[0];
  const int*   seq_pos = (const int*)d_in[1];
  const float* wq  = (const float*)d_in[2];
  const float* bq  = (const float*)d_in[3];
  const float* wkv = (const float*)d_in[4];
  const float* bkv = (const float*)d_in[5];
  const float* wo  = (const float*)d_in[6];
  const float* bo  = (const float*)d_in[7];
  float* out = (float*)d_out;

  char* ws = (char*)d_ws;
  unsigned short* Abf     = (unsigned short*)(ws + 0);          // 16.78 MB
  unsigned short* WqkvT   = (unsigned short*)(ws + 16777216);   // 12.58 MB
  unsigned short* WoT     = (unsigned short*)(ws + 29360128);   // 8.39 MB
  float*          biasqkv = (float*)(ws + 37748736);            // 12 KB
  unsigned short* QKVraw  = (unsigned short*)(ws + 37761024);   // 25.17 MB
  unsigned short* Qr      = (unsigned short*)(ws + 62926848);   // 16.78 MB
  unsigned short* Kr      = (unsigned short*)(ws + 79704064);   // 4.19 MB
  unsigned short* Vt      = (unsigned short*)(ws + 83898368);   // 4.19 MB
  unsigned short* Xb      = (unsigned short*)(ws + 88092672);   // 16.78 MB  (end ~104.9 MB)

  f32_to_bf16_vec<<<8192, 256, 0, stream>>>(inputs, Abf, (NB * SEQ * DM) / 4);
  transpose_f32_to_bf16<<<dim3(64, 64), dim3(32, 8), 0, stream>>>(wq, WqkvT, DM, 2048);
  transpose_f32_to_bf16<<<dim3(32, 64), dim3(32, 8), 0, stream>>>(wkv, WqkvT + (size_t)2048 * DM, DM, 1024);
  transpose_f32_to_bf16<<<dim3(64, 64), dim3(32, 8), 0, stream>>>(wo, WoT, DM, 2048);
  bias_concat<<<12, 256, 0, stream>>>(bq, bkv, biasqkv);

  gemm_bt<unsigned short><<<dim3(NQKV / 128, MROWS / 128), 256, 0, stream>>>(
      Abf, WqkvT, biasqkv, QKVraw, MROWS, NQKV, DM);

  rope_scatter<<<NB * SEQ, 64, 0, stream>>>(QKVraw, seq_pos, Qr, Kr);
  v_transpose<<<NB * NKVH * (SEQ / 64), 256, 0, stream>>>(QKVraw, Vt);

  flash_attn<<<dim3(SEQ / 64, NB * NH), 256, 0, stream>>>(Qr, Kr, Vt, seq_pos, Xb);

  gemm_bt<float><<<dim3(DM / 128, MROWS / 128), 256, 0, stream>>>(
      Xb, WoT, bo, out, MROWS, DM, DM);
}

// Round 2
// 396.287 us; speedup vs baseline: 1.2511x; 1.2511x over previous
//
#include <hip/hip_runtime.h>
#include <hip/hip_bf16.h>

// Problem dims
#define DM    2048
#define SEQ   2048
#define NB    2
#define NH    16
#define NKVH  4
#define HD    128
#define NQKV  3072   // 2048 q cols + 1024 kv cols
#define MROWS 4096   // B*S
#define KVB   64

using f32x4  = __attribute__((ext_vector_type(4))) float;
using short8 = __attribute__((ext_vector_type(8))) short;
using ushort8 = __attribute__((ext_vector_type(8))) unsigned short;

static __device__ __forceinline__ unsigned short f2bf(float f) {
  __hip_bfloat16 h = __float2bfloat16(f);
  return *reinterpret_cast<unsigned short*>(&h);
}
static __device__ __forceinline__ float bf2f(unsigned short u) {
  union { unsigned int i; float f; } v; v.i = ((unsigned int)u) << 16; return v.f;
}

// async global->LDS, 16B per lane; LDS dest is wave-uniform base + lane*16
typedef __attribute__((address_space(1))) const unsigned char as1_c;
typedef __attribute__((address_space(3))) unsigned char as3_c;
static __device__ __forceinline__ void gload_lds16(const void* g, void* l) {
  __builtin_amdgcn_global_load_lds((as1_c*)g, (as3_c*)l, 16, 0, 0);
}

// ---------------- elementwise converts / transposes ----------------

__global__ void f32_to_bf16_vec(const float* __restrict__ src, unsigned short* __restrict__ dst, int n4) {
  int i = blockIdx.x * blockDim.x + threadIdx.x;
  if (i < n4) {
    float4 v = reinterpret_cast<const float4*>(src)[i];
    ushort4 o;
    o.x = f2bf(v.x); o.y = f2bf(v.y); o.z = f2bf(v.z); o.w = f2bf(v.w);
    reinterpret_cast<ushort4*>(dst)[i] = o;
  }
}

// dst[n][k] = bf16(src[k][n]);  src is [K][N] f32 row-major, dst rows have stride K
__global__ void transpose_f32_to_bf16(const float* __restrict__ src, unsigned short* __restrict__ dst,
                                      int K, int N) {
  __shared__ float t[32][33];
  int n0 = blockIdx.x * 32, k0 = blockIdx.y * 32;
  int tx = threadIdx.x, ty = threadIdx.y;  // 32 x 8
  for (int j = 0; j < 4; j++)
    t[ty + j * 8][tx] = src[(size_t)(k0 + ty + j * 8) * N + n0 + tx];
  __syncthreads();
  for (int j = 0; j < 4; j++)
    dst[(size_t)(n0 + ty + j * 8) * K + k0 + tx] = f2bf(t[tx][ty + j * 8]);
}

__global__ void bias_concat(const float* __restrict__ bq, const float* __restrict__ bkv, float* __restrict__ o) {
  int i = blockIdx.x * 256 + threadIdx.x;
  if (i < NQKV) o[i] = (i < DM) ? bq[i] : bkv[i - DM];
}

// ------------- bf16 MFMA GEMM (m97 structure): C = A * Bt^T + bias -------------

static __device__ __forceinline__ void storeval(float* C, size_t i, float v) { C[i] = v; }
static __device__ __forceinline__ void storeval(unsigned short* C, size_t i, float v) { C[i] = f2bf(v); }

template <typename OutT>
__global__ __launch_bounds__(256) void gemm_bt(const unsigned short* __restrict__ A,
                                               const unsigned short* __restrict__ Bt,
                                               const float* __restrict__ bias,
                                               OutT* __restrict__ C, int M, int N, int K) {
  // 128x128 tile, BK=64, linear LDS (global_load_lds requires contiguous dest)
  __shared__ __align__(16) unsigned short la[128 * 64];
  __shared__ __align__(16) unsigned short lb[128 * 64];
  int tid = threadIdx.x, lane = tid & 63, w = tid >> 6;
  int wr = w >> 1, wc = w & 1, lg = lane >> 4, ln = lane & 15;
  int m0 = blockIdx.y * 128, n0 = blockIdx.x * 128;

  f32x4 acc[4][4];
  for (int mi = 0; mi < 4; mi++)
    for (int ni = 0; ni < 4; ni++) acc[mi][ni] = (f32x4){0, 0, 0, 0};

  int srow = lane >> 3;         // 0..7 within 8-row slab
  int scol = (lane & 7) * 8;    // element col
  const unsigned short* ga = A + (size_t)(m0 + w * 32 + srow) * K + scol;
  const unsigned short* gb = Bt + (size_t)(n0 + w * 32 + srow) * K + scol;
  unsigned short* lab = &la[(w * 32) * 64];  // wave-uniform LDS bases
  unsigned short* lbb = &lb[(w * 32) * 64];

  for (int kt = 0; kt < K; kt += 64) {
#pragma unroll
    for (int i = 0; i < 4; i++) {
      gload_lds16(ga + (size_t)i * 8 * K + kt, lab + i * 8 * 64);
      gload_lds16(gb + (size_t)i * 8 * K + kt, lbb + i * 8 * 64);
    }
    __syncthreads();
#pragma unroll
    for (int kk = 0; kk < 64; kk += 32) {
      short8 af[4], bfr[4];
#pragma unroll
      for (int mi = 0; mi < 4; mi++)
        af[mi] = *reinterpret_cast<const short8*>(&la[(wr * 64 + mi * 16 + ln) * 64 + kk + lg * 8]);
#pragma unroll
      for (int ni = 0; ni < 4; ni++)
        bfr[ni] = *reinterpret_cast<const short8*>(&lb[(wc * 64 + ni * 16 + ln) * 64 + kk + lg * 8]);
#pragma unroll
      for (int mi = 0; mi < 4; mi++)
#pragma unroll
        for (int ni = 0; ni < 4; ni++)
          acc[mi][ni] = __builtin_amdgcn_mfma_f32_16x16x32_bf16(af[mi], bfr[ni], acc[mi][ni], 0, 0, 0);
    }
    __syncthreads();
  }
  for (int mi = 0; mi < 4; mi++) {
    int mrow = m0 + wr * 64 + mi * 16 + lg * 4;
    for (int ni = 0; ni < 4; ni++) {
      int n = n0 + wc * 64 + ni * 16 + ln;
      float bv = bias ? bias[n] : 0.0f;
      for (int r4 = 0; r4 < 4; r4++)
        storeval(C, (size_t)(mrow + r4) * N + n, acc[mi][ni][r4] + bv);
    }
  }
}

// ---------------- RoPE + scatter Q,K ----------------

__global__ void rope_scatter(const unsigned short* __restrict__ QKVraw, const int* __restrict__ seq_pos,
                             unsigned short* __restrict__ Qo, unsigned short* __restrict__ Ko) {
  int bs = blockIdx.x;              // b*SEQ + s
  int b = bs >> 11, s = bs & (SEQ - 1);
  int i = threadIdx.x;              // 0..63 (one wave)
  float pos = (float)seq_pos[bs];
  float ts = powf(10000.0f, (float)i * (1.0f / 64.0f));
  float ang = pos / ts;
  float sn, cs;
  sincosf(ang, &sn, &cs);
  const unsigned short* raw = QKVraw + (size_t)bs * NQKV;
  const float qscale = 0.08838834764831845f;  // 1/sqrt(128)
  for (int h = 0; h < NH; h++) {
    float x1 = bf2f(raw[h * HD + i]);
    float x2 = bf2f(raw[h * HD + 64 + i]);
    size_t o = ((size_t)((b * NH + h) * SEQ + s)) * HD;
    Qo[o + i]      = f2bf((x1 * cs - x2 * sn) * qscale);
    Qo[o + 64 + i] = f2bf((x2 * cs + x1 * sn) * qscale);
  }
  for (int kh = 0; kh < NKVH; kh++) {
    int base = DM + kh * 256;
    float x1 = bf2f(raw[base + i]);
    float x2 = bf2f(raw[base + 64 + i]);
    size_t o = ((size_t)((b * NKVH + kh) * SEQ + s)) * HD;
    Ko[o + i]      = f2bf(x1 * cs - x2 * sn);
    Ko[o + 64 + i] = f2bf(x2 * cs + x1 * sn);
  }
}

// ---------------- V transpose: Vt[b][kv][d][s] ----------------

__global__ __launch_bounds__(256) void v_transpose(const unsigned short* __restrict__ QKVraw,
                                                   unsigned short* __restrict__ Vt) {
  __shared__ __align__(16) unsigned short lv[64][136];
  int blk = blockIdx.x;           // (b*NKVH+kvh)*32 + s_tile
  int bkv = blk >> 5;
  int s0 = (blk & 31) * 64;
  int b = bkv >> 2, kvh = bkv & 3;
  int tid = threadIdx.x;
  {
    int sl = tid >> 4, cl = (tid & 15) * 8;
    for (int p = 0; p < 4; p++) {
      int srow = sl + p * 16;
      *reinterpret_cast<uint4*>(&lv[srow][cl]) = *reinterpret_cast<const uint4*>(
          QKVraw + (size_t)(b * SEQ + s0 + srow) * NQKV + DM + kvh * 256 + 128 + cl);
    }
  }
  __syncthreads();
  {
    int dl = tid >> 3, so = (tid & 7) * 8;
    for (int p = 0; p < 4; p++) {
      int d = dl + p * 32;
      ushort8 t8;
      for (int j = 0; j < 8; j++) t8[j] = lv[so + j][d];
      *reinterpret_cast<ushort8*>(Vt + (size_t)(bkv * HD + d) * SEQ + s0 + so) = t8;
    }
  }
}

// ---------------- causal GQA flash attention v2 ----------------
// grid (S/128, B*NH): block handles q-tiles {bx, 31-bx} (work pairing -> 33 KV iters each).
// 4 waves x 16 q-rows, KVBLK=64, XOR-swizzled LDS.

__global__ __launch_bounds__(256) void flash_attn(const unsigned short* __restrict__ Q,
                                                  const unsigned short* __restrict__ Kr,
                                                  const unsigned short* __restrict__ Vt,
                                                  const int* __restrict__ seq_pos,
                                                  unsigned short* __restrict__ X) {
  __shared__ __align__(16) unsigned short lds_k[64 * 128];   // [kv][d] swizzled
  __shared__ __align__(16) unsigned short lds_v[128 * 64];   // [d][kv] swizzled
  __shared__ __align__(16) unsigned short lds_p[4][16 * 64]; // per-wave P swizzled
  int tid = threadIdx.x, lane = tid & 63, w = tid >> 6;
  int bh = blockIdx.y, b = bh >> 4, h = bh & 15, kvh = h >> 2;
  int lg = lane >> 4, ln = lane & 15;

  const unsigned short* kbase = Kr + ((size_t)(b * NKVH + kvh)) * SEQ * HD;
  const unsigned short* vbase = Vt + ((size_t)(b * NKVH + kvh)) * HD * SEQ;

  // staging assignments
  int krow = tid >> 2, kc0 = (tid & 3) * 32;  // K: 64 rows, 4x16B chunks/thread
  int ksw = (krow & 7) << 4;
  int vrow = tid >> 1, vc0 = (tid & 1) * 32;  // V: 128 rows, 4x16B chunks/thread
  int vsw = (vrow & 7) << 4;

  for (int pass = 0; pass < 2; pass++) {
    int qtile = (pass == 0) ? (int)blockIdx.x : (SEQ / 64 - 1 - (int)blockIdx.x);
    int qblk = qtile * 64;
    int q0w = qblk + w * 16;

    // block-uniform causal bound
    int pmax = seq_pos[b * SEQ + qblk + lane];
    for (int o = 32; o; o >>= 1) { int t2 = __shfl_xor(pmax, o); pmax = pmax > t2 ? pmax : t2; }
    int ntiles = (pmax + KVB) >> 6;
    if (ntiles > SEQ / KVB) ntiles = SEQ / KVB;

    int pos_r[4];
    for (int r = 0; r < 4; r++) pos_r[r] = seq_pos[b * SEQ + q0w + lg * 4 + r];

    short8 qf[4];
    {
      const unsigned short* qp = Q + ((size_t)((b * NH + h) * SEQ + q0w + ln)) * HD;
      for (int c = 0; c < 4; c++) qf[c] = *reinterpret_cast<const short8*>(qp + c * 32 + lg * 8);
    }

    f32x4 acc[8];
    for (int dt = 0; dt < 8; dt++) acc[dt] = (f32x4){0, 0, 0, 0};
    float m_r[4] = {-1e30f, -1e30f, -1e30f, -1e30f};
    float l_r[4] = {0, 0, 0, 0};

    for (int t = 0; t < ntiles; t++) {
      int kv0 = t * KVB;
      // stage K and V tiles (reg-staged, swizzled ds_write_b128)
      {
        const unsigned short* gk = kbase + (size_t)(kv0 + krow) * HD + kc0;
        const unsigned short* gv = vbase + (size_t)vrow * SEQ + kv0 + vc0;
        char* lk = (char*)lds_k + krow * 256;
        char* lv = (char*)lds_v + vrow * 128;
#pragma unroll
        for (int j = 0; j < 4; j++) {
          uint4 kd = *reinterpret_cast<const uint4*>(gk + j * 8);
          uint4 vd = *reinterpret_cast<const uint4*>(gv + j * 8);
          *reinterpret_cast<uint4*>(lk + ((kc0 * 2 + j * 16) ^ ksw)) = kd;
          *reinterpret_cast<uint4*>(lv + ((vc0 * 2 + j * 16) ^ vsw)) = vd;
        }
      }
      __syncthreads();

      // QK^T: S tile 16(q) x 64(kv)
      f32x4 sa[4];
#pragma unroll
      for (int ct = 0; ct < 4; ct++) {
        sa[ct] = (f32x4){0, 0, 0, 0};
        int row = ct * 16 + ln;
        const char* kr0 = (const char*)lds_k + row * 256;
        int sw = (row & 7) << 4;
#pragma unroll
        for (int c = 0; c < 4; c++) {
          short8 kf = *reinterpret_cast<const short8*>(kr0 + ((c * 64 + lg * 16) ^ sw));
          sa[ct] = __builtin_amdgcn_mfma_f32_16x16x32_bf16(qf[c], kf, sa[ct], 0, 0, 0);
        }
      }

      // online softmax (mask via -1e30; __expf underflows to 0 for masked lanes)
      float p[4][4], corr[4];
#pragma unroll
      for (int r = 0; r < 4; r++) {
        int kv = kv0 + ln;
        float v0 = (kv      <= pos_r[r]) ? sa[0][r] : -1e30f;
        float v1 = (kv + 16 <= pos_r[r]) ? sa[1][r] : -1e30f;
        float v2 = (kv + 32 <= pos_r[r]) ? sa[2][r] : -1e30f;
        float v3 = (kv + 48 <= pos_r[r]) ? sa[3][r] : -1e30f;
        float tmx = fmaxf(fmaxf(v0, v1), fmaxf(v2, v3));
        tmx = fmaxf(tmx, __shfl_xor(tmx, 1));
        tmx = fmaxf(tmx, __shfl_xor(tmx, 2));
        tmx = fmaxf(tmx, __shfl_xor(tmx, 4));
        tmx = fmaxf(tmx, __shfl_xor(tmx, 8));
        float nm = fmaxf(m_r[r], tmx);
        corr[r] = __expf(m_r[r] - nm);
        float p0 = __expf(v0 - nm), p1 = __expf(v1 - nm);
        float p2 = __expf(v2 - nm), p3 = __expf(v3 - nm);
        m_r[r] = nm;
        p[0][r] = p0; p[1][r] = p1; p[2][r] = p2; p[3][r] = p3;
        float rs = (p0 + p1) + (p2 + p3);
        rs += __shfl_xor(rs, 1); rs += __shfl_xor(rs, 2);
        rs += __shfl_xor(rs, 4); rs += __shfl_xor(rs, 8);
        l_r[r] = l_r[r] * corr[r] + rs;
      }

      // P -> per-wave swizzled LDS
      {
        char* pw = (char*)lds_p[w];
#pragma unroll
        for (int r = 0; r < 4; r++) {
          int row = lg * 4 + r;
          int sw2 = (row & 7) << 4;
          char* pr = pw + row * 128;
#pragma unroll
          for (int ct = 0; ct < 4; ct++)
            *reinterpret_cast<unsigned short*>(pr + (((ct * 16 + ln) * 2) ^ sw2)) = f2bf(p[ct][r]);
        }
      }
      asm volatile("s_waitcnt lgkmcnt(0)" ::: "memory");
      __builtin_amdgcn_sched_barrier(0);
      short8 pf[2];
      {
        const char* pr = (const char*)lds_p[w] + ln * 128;
        int sw2 = (ln & 7) << 4;
        pf[0] = *reinterpret_cast<const short8*>(pr + ((lg * 16) ^ sw2));
        pf[1] = *reinterpret_cast<const short8*>(pr + ((64 + lg * 16) ^ sw2));
      }

#pragma unroll
      for (int dt = 0; dt < 8; dt++)
#pragma unroll
        for (int r = 0; r < 4; r++) acc[dt][r] *= corr[r];

      // PV
#pragma unroll
      for (int dt = 0; dt < 8; dt++) {
        int row = dt * 16 + ln;
        const char* vr0 = (const char*)lds_v + row * 128;
        int sw3 = (row & 7) << 4;
        short8 vf0 = *reinterpret_cast<const short8*>(vr0 + ((lg * 16) ^ sw3));
        short8 vf1 = *reinterpret_cast<const short8*>(vr0 + ((64 + lg * 16) ^ sw3));
        acc[dt] = __builtin_amdgcn_mfma_f32_16x16x32_bf16(pf[0], vf0, acc[dt], 0, 0, 0);
        acc[dt] = __builtin_amdgcn_mfma_f32_16x16x32_bf16(pf[1], vf1, acc[dt], 0, 0, 0);
      }
      __syncthreads();
    }

    // epilogue (registers only; safe to overlap with next pass staging)
    for (int r = 0; r < 4; r++) {
      float inv = l_r[r] > 0.0f ? 1.0f / l_r[r] : 0.0f;
      int qrow = q0w + lg * 4 + r;
      unsigned short* xp = X + ((size_t)(b * SEQ + qrow)) * DM + h * HD;
      for (int dt = 0; dt < 8; dt++) xp[dt * 16 + ln] = f2bf(acc[dt][r] * inv);
    }
  }
}

// ---------------- launch ----------------

extern "C" void kernel_launch(void* const* d_in, const int* in_sizes, int n_in,
                              void* d_out, int out_size, void* d_ws, size_t ws_size,
                              hipStream_t stream) {
  const float* inputs  = (const float*)d_in[0];
  const int*   seq_pos = (const int*)d_in[1];
  const float* wq  = (const float*)d_in[2];
  const float* bq  = (const float*)d_in[3];
  const float* wkv = (const float*)d_in[4];
  const float* bkv = (const float*)d_in[5];
  const float* wo  = (const float*)d_in[6];
  const float* bo  = (const float*)d_in[7];
  float* out = (float*)d_out;

  char* ws = (char*)d_ws;
  unsigned short* Abf     = (unsigned short*)(ws + 0);          // 16.78 MB
  unsigned short* WqkvT   = (unsigned short*)(ws + 16777216);   // 12.58 MB
  unsigned short* WoT     = (unsigned short*)(ws + 29360128);   // 8.39 MB
  float*          biasqkv = (float*)(ws + 37748736);            // 12 KB
  unsigned short* QKVraw  = (unsigned short*)(ws + 37761024);   // 25.17 MB
  unsigned short* Qr      = (unsigned short*)(ws + 62926848);   // 16.78 MB
  unsigned short* Kr      = (unsigned short*)(ws + 79704064);   // 4.19 MB
  unsigned short* Vt      = (unsigned short*)(ws + 83898368);   // 4.19 MB
  unsigned short* Xb      = (unsigned short*)(ws + 88092672);   // 16.78 MB  (end ~104.9 MB)

  f32_to_bf16_vec<<<8192, 256, 0, stream>>>(inputs, Abf, (NB * SEQ * DM) / 4);
  transpose_f32_to_bf16<<<dim3(64, 64), dim3(32, 8), 0, stream>>>(wq, WqkvT, DM, 2048);
  transpose_f32_to_bf16<<<dim3(32, 64), dim3(32, 8), 0, stream>>>(wkv, WqkvT + (size_t)2048 * DM, DM, 1024);
  transpose_f32_to_bf16<<<dim3(64, 64), dim3(32, 8), 0, stream>>>(wo, WoT, DM, 2048);
  bias_concat<<<12, 256, 0, stream>>>(bq, bkv, biasqkv);

  gemm_bt<unsigned short><<<dim3(NQKV / 128, MROWS / 128), 256, 0, stream>>>(
      Abf, WqkvT, biasqkv, QKVraw, MROWS, NQKV, DM);

  rope_scatter<<<NB * SEQ, 64, 0, stream>>>(QKVraw, seq_pos, Qr, Kr);
  v_transpose<<<NB * NKVH * (SEQ / 64), 256, 0, stream>>>(QKVraw, Vt);

  flash_attn<<<dim3(SEQ / 128, NB * NH), 256, 0, stream>>>(Qr, Kr, Vt, seq_pos, Xb);

  gemm_bt<float><<<dim3(DM / 128, MROWS / 128), 256, 0, stream>>>(
      Xb, WoT, bo, out, MROWS, DM, DM);
}